// Round 4
// baseline (49888.141 us; speedup 1.0000x reference)
//
#include <hip/hip_runtime.h>
#include <math.h>

#define NLFULL 504
#define REAL_NL 500
#define BATCH 2048
#define NZ 50
#define NC 21
#define GHID 512
#define EPSB 1e-5f
#define LO_SCALE 2048.0f
#define INV_LO (1.0f / 2048.0f)

typedef __attribute__((ext_vector_type(4))) float f32x4;
typedef __attribute__((ext_vector_type(8))) _Float16 half8;

__device__ __forceinline__ void split2(float x, _Float16& hi, _Float16& lo) {
    hi = (_Float16)x;
    lo = (_Float16)((x - (float)hi) * LO_SCALE);
}

// =============================== upsample ==================================
__global__ __launch_bounds__(512) void upsample_kernel(
    const float* __restrict__ z, const float* __restrict__ dW, const float* __restrict__ db,
    const float* __restrict__ W0, const float* __restrict__ g0, const float* __restrict__ bb0,
    const float* __restrict__ m0, const float* __restrict__ v0, const float* __restrict__ al0,
    const float* __restrict__ W1, const float* __restrict__ g1, const float* __restrict__ bb1,
    const float* __restrict__ m1, const float* __restrict__ v1, const float* __restrict__ al1,
    const float* __restrict__ W2, const float* __restrict__ g2, const float* __restrict__ bb2,
    const float* __restrict__ m2, const float* __restrict__ v2, const float* __restrict__ al2,
    float* __restrict__ hseq)
{
    __shared__ float bufA[5712];   // u: [336][17]   then w: [84][65]
    __shared__ float bufB[5544];   // v: [168][33]
    __shared__ float zl[52];

    const int b   = blockIdx.x;
    const int ta  = blockIdx.y * 16;
    const int nt0 = min(16, 63 - ta);
    const int tid = threadIdx.x;

    if (tid < NZ) zl[tid] = z[b * NZ + tid];
    __syncthreads();

    for (int i = tid; i < 336 * nt0; i += 512) {
        int c = i % 336, tt = i / 336;
        int row = c * 63 + ta + tt;
        const float* wr = dW + (size_t)row * NZ;
        float s = db[row];
        #pragma unroll
        for (int n = 0; n < NZ; ++n) s += zl[n] * wr[n];
        bufA[c * 17 + tt] = s;
    }
    __syncthreads();

    const float a0 = al0[0], a1 = al1[0], a2 = al2[0];

    for (int i = tid; i < 168 * 2 * nt0; i += 512) {
        int o = i % 168, tt1 = i / 168;
        int tt = tt1 >> 1, k = tt1 & 1;
        const float* wp = W0 + o * 2 + k;
        float s = 0.f;
        for (int c = 0; c < 336; ++c) s += bufA[c * 17 + tt] * wp[c * 336];
        float sc = g0[o] / sqrtf(v0[o] + EPSB);
        s = (s - m0[o]) * sc + bb0[o];
        s = (s >= 0.f) ? s : a0 * s;
        bufB[o * 33 + tt1] = s;
    }
    __syncthreads();

    for (int i = tid; i < 84 * 4 * nt0; i += 512) {
        int o = i % 84, tt2 = i / 84;
        int tt1 = tt2 >> 1, k = tt2 & 1;
        const float* wp = W1 + o * 2 + k;
        float s = 0.f;
        for (int c = 0; c < 168; ++c) s += bufB[c * 33 + tt1] * wp[c * 168];
        float sc = g1[o] / sqrtf(v1[o] + EPSB);
        s = (s - m1[o]) * sc + bb1[o];
        s = (s >= 0.f) ? s : a1 * s;
        bufA[o * 65 + tt2] = s;
    }
    __syncthreads();

    for (int i = tid; i < 42 * 8 * nt0; i += 512) {
        int o = i % 42, tt3 = i / 42;
        int tt2 = tt3 >> 1, k = tt3 & 1;
        const float* wp = W2 + o * 2 + k;
        float s = 0.f;
        for (int c = 0; c < 84; ++c) s += bufA[c * 65 + tt2] * wp[c * 84];
        float sc = g2[o] / sqrtf(v2[o] + EPSB);
        s = (s - m2[o]) * sc + bb2[o];
        s = (s >= 0.f) ? s : a2 * s;
        int t3 = 8 * ta + tt3;
        hseq[(size_t)t3 * (BATCH * 42) + b * 42 + o] = s;
    }
}

// ================= table: gi-contribution of one-hot px =====================
__global__ void table_kernel(const float* __restrict__ w_px, const float* __restrict__ b_px,
                             const float* __restrict__ w_ih, const float* __restrict__ b_ih,
                             float* __restrict__ table)
{
    int i = blockIdx.x * 256 + threadIdx.x;
    if (i >= 22 * 1536) return;
    int e = i / 1536, jg = i % 1536;
    const float* wih = w_ih + jg * 63 + 42;
    float s = b_ih[jg];
    #pragma unroll
    for (int jp = 0; jp < NC; ++jp) {
        float px = b_px[jp] + (e < NC ? w_px[jp * NC + e] : 0.f);
        s += px * wih[jp];
    }
    table[i] = s;
}

// ====== pack weights into MFMA B-fragment order, fp16 2-limb (lo x2048) =====
// whh pack layout: [g][nf(32)][kf(16)][lane(64)*8]
// B-frag: lane l supplies B[k=(l>>4)*8+e][n=l&15] = w[n][k]
__global__ void pack_whh_kernel(const float* __restrict__ w_hh,
                                _Float16* __restrict__ pH, _Float16* __restrict__ pL)
{
    int i = blockIdx.x * 256 + threadIdx.x;
    if (i >= 3 * 32 * 16 * 512) return;
    int e = i & 7, l = (i >> 3) & 63, kf = (i >> 9) & 15, nf = (i >> 13) & 31, g = i >> 18;
    int n = nf * 16 + (l & 15);
    int k = kf * 32 + ((l >> 4) << 3) + e;
    float v = w_hh[(size_t)(g * GHID + n) * GHID + k];
    _Float16 hi, lo; split2(v, hi, lo);
    pH[i] = hi; pL[i] = lo;
}

// wih pack layout: [g][nf(32)][kf(2)][lane(64)*8], K padded 42 -> 64 with zeros
__global__ void pack_wih_kernel(const float* __restrict__ w_ih,
                                _Float16* __restrict__ pH, _Float16* __restrict__ pL)
{
    int i = blockIdx.x * 256 + threadIdx.x;
    if (i >= 3 * 32 * 2 * 512) return;
    int e = i & 7, l = (i >> 3) & 63, kf = (i >> 9) & 1, nf = (i >> 10) & 31, g = i >> 15;
    int n = nf * 16 + (l & 15);
    int k = kf * 32 + ((l >> 4) << 3) + e;
    float v = (k < 42) ? w_ih[(size_t)(g * GHID + n) * 63 + k] : 0.f;
    _Float16 hi, lo; split2(v, hi, lo);
    pH[i] = hi; pL[i] = lo;
}

// ===================== init h0 (fp16 2-limb), idx ===========================
__global__ void init_kernel(_Float16* __restrict__ hH, _Float16* __restrict__ hL,
                            int* __restrict__ idx)
{
    int i = blockIdx.x * 256 + threadIdx.x;
    if (i < BATCH * GHID) { hH[i] = (_Float16)0.f; hL[i] = (_Float16)0.f; }
    if (i < BATCH) idx[i] = NC;
}

// ================= GRU gates (MFMA fp16 2-limb / 3-product) =================
// block = 256 thr = 4 waves (2M x 2N); wave tile 32M x 32N x 3 gates.
// grid (8 n-tiles, 32 m-tiles): gridDim.x=8 -> XCD id == n-tile (B L2-resident).
// main += aH*bH ; cross += aH*bL + aL*bH ; val = main + cross/2048.
#define MFMA3(mainA, crossA, aH_, aL_, bH_, bL_)                                   \
    mainA  = __builtin_amdgcn_mfma_f32_16x16x32_f16(aH_, bH_, mainA, 0, 0, 0);     \
    crossA = __builtin_amdgcn_mfma_f32_16x16x32_f16(aH_, bL_, crossA, 0, 0, 0);    \
    crossA = __builtin_amdgcn_mfma_f32_16x16x32_f16(aL_, bH_, crossA, 0, 0, 0);

__global__ __launch_bounds__(256) void gru_gates_mfma(
    const _Float16* __restrict__ hpH, const _Float16* __restrict__ hpL,
    const float* __restrict__ ht,   // hseq + t*B*42
    const int* __restrict__ idx, const float* __restrict__ table,
    const _Float16* __restrict__ whhH, const _Float16* __restrict__ whhL,
    const _Float16* __restrict__ wihH, const _Float16* __restrict__ wihL,
    const float* __restrict__ b_hh,
    _Float16* __restrict__ hnH, _Float16* __restrict__ hnL)
{
    const int l   = threadIdx.x & 63;
    const int wv  = threadIdx.x >> 6;     // 0..3
    const int wM  = wv >> 1, wN = wv & 1;
    const int m0  = blockIdx.y * 64 + wM * 32;
    const int nfB = blockIdx.x * 4 + wN * 2;    // first of 2 n-frags
    const int lrow = l & 15;
    const int lk = (l >> 4) << 3;

    f32x4 aRZ[2][2][2], xRZ[2][2][2];   // [r|z][mi][ni]  main / cross
    f32x4 aIN[2][2], xIN[2][2];         // n-gate input part
    f32x4 aHN[2][2], xHN[2][2];         // n-gate hidden part
    #pragma unroll
    for (int a = 0; a < 2; ++a)
        #pragma unroll
        for (int b = 0; b < 2; ++b) {
            aRZ[0][a][b] = (f32x4)0.f; aRZ[1][a][b] = (f32x4)0.f;
            xRZ[0][a][b] = (f32x4)0.f; xRZ[1][a][b] = (f32x4)0.f;
            aIN[a][b] = (f32x4)0.f; xIN[a][b] = (f32x4)0.f;
            aHN[a][b] = (f32x4)0.f; xHN[a][b] = (f32x4)0.f;
        }

    const size_t arow0 = (size_t)(m0 + lrow) * GHID + lk;
    const size_t arow1 = arow0 + 16 * GHID;

    // ---- H part: K = 512 = 16 k-frags ----
    #pragma unroll 2
    for (int kf = 0; kf < 16; ++kf) {
        half8 aH[2], aL[2];
        aH[0] = *(const half8*)(hpH + arow0 + kf * 32);
        aL[0] = *(const half8*)(hpL + arow0 + kf * 32);
        aH[1] = *(const half8*)(hpH + arow1 + kf * 32);
        aL[1] = *(const half8*)(hpL + arow1 + kf * 32);
        #pragma unroll
        for (int g = 0; g < 3; ++g) {
            #pragma unroll
            for (int ni = 0; ni < 2; ++ni) {
                size_t boff = ((size_t)((g * 32 + nfB + ni) * 16 + kf) << 9) + (l << 3);
                half8 bH = *(const half8*)(whhH + boff);
                half8 bL = *(const half8*)(whhL + boff);
                #pragma unroll
                for (int mi = 0; mi < 2; ++mi) {
                    f32x4* am = (g == 2) ? &aHN[mi][ni] : &aRZ[g][mi][ni];
                    f32x4* xm = (g == 2) ? &xHN[mi][ni] : &xRZ[g][mi][ni];
                    MFMA3((*am), (*xm), aH[mi], aL[mi], bH, bL);
                }
            }
        }
    }

    // ---- I part: K = 42 (2 k-frags, on-the-fly fp32 -> 2-limb split) ----
    #pragma unroll
    for (int kf = 0; kf < 2; ++kf) {
        half8 aH[2], aL[2];
        #pragma unroll
        for (int mi = 0; mi < 2; ++mi) {
            const float* rp = ht + (size_t)(m0 + mi * 16 + lrow) * 42;
            #pragma unroll
            for (int e = 0; e < 8; ++e) {
                int k = kf * 32 + lk + e;
                float f = (k < 42) ? rp[k] : 0.f;
                _Float16 hi, lo; split2(f, hi, lo);
                aH[mi][e] = hi; aL[mi][e] = lo;
            }
        }
        #pragma unroll
        for (int g = 0; g < 3; ++g) {
            #pragma unroll
            for (int ni = 0; ni < 2; ++ni) {
                size_t boff = ((size_t)((g * 32 + nfB + ni) * 2 + kf) << 9) + (l << 3);
                half8 bH = *(const half8*)(wihH + boff);
                half8 bL = *(const half8*)(wihL + boff);
                #pragma unroll
                for (int mi = 0; mi < 2; ++mi) {
                    f32x4* am = (g == 2) ? &aIN[mi][ni] : &aRZ[g][mi][ni];
                    f32x4* xm = (g == 2) ? &xIN[mi][ni] : &xRZ[g][mi][ni];
                    MFMA3((*am), (*xm), aH[mi], aL[mi], bH, bL);
                }
            }
        }
    }

    // ---- epilogue: D layout row=(l>>4)*4+r, col=l&15 ----
    #pragma unroll
    for (int ni = 0; ni < 2; ++ni) {
        int c = (nfB + ni) * 16 + lrow;
        float bhr = b_hh[c], bhz = b_hh[GHID + c], bhn = b_hh[2 * GHID + c];
        #pragma unroll
        for (int mi = 0; mi < 2; ++mi) {
            #pragma unroll
            for (int r = 0; r < 4; ++r) {
                int m = m0 + mi * 16 + ((l >> 4) << 2) + r;
                const float* tb = table + idx[m] * 1536;
                float rv = aRZ[0][mi][ni][r] + xRZ[0][mi][ni][r] * INV_LO + bhr + tb[c];
                float zv = aRZ[1][mi][ni][r] + xRZ[1][mi][ni][r] * INV_LO + bhz + tb[GHID + c];
                float rg = 1.f / (1.f + expf(-rv));
                float zg = 1.f / (1.f + expf(-zv));
                float hnp = aHN[mi][ni][r] + xHN[mi][ni][r] * INV_LO + bhn;
                float inp = aIN[mi][ni][r] + xIN[mi][ni][r] * INV_LO + tb[2 * GHID + c];
                float ng = tanhf(inp + rg * hnp);
                size_t off = (size_t)m * GHID + c;
                float hpv = (float)hpH[off] + (float)hpL[off] * INV_LO;
                float hnv = (1.f - zg) * ng + zg * hpv;
                _Float16 hi, lo; split2(hnv, hi, lo);
                hnH[off] = hi; hnL[off] = lo;
            }
        }
    }
}

// ============== logits + argmax (64 rows/block, w_out in LDS) ===============
__global__ __launch_bounds__(256) void gru_logits(
    const _Float16* __restrict__ hH, const _Float16* __restrict__ hL,
    const float* __restrict__ w_out, const float* __restrict__ b_out,
    float* __restrict__ out, int* __restrict__ idx, int t)
{
    __shared__ float wsm[NC * GHID];   // 43 KB
    const int tid = threadIdx.x;
    for (int i = tid; i < NC * GHID; i += 256) wsm[i] = w_out[i];
    __syncthreads();

    const int r = tid >> 2, q = tid & 3;
    const int row = blockIdx.x * 64 + r;
    const _Float16* ph = hH + (size_t)row * GHID + q * 128;
    const _Float16* pl = hL + (size_t)row * GHID + q * 128;

    float acc[NC];
    #pragma unroll
    for (int c = 0; c < NC; ++c) acc[c] = 0.f;

    for (int kk = 0; kk < 128; ++kk) {
        float hval = (float)ph[kk] + (float)pl[kk] * INV_LO;
        const float* wp = wsm + q * 128 + kk;
        #pragma unroll
        for (int c = 0; c < NC; ++c) acc[c] += hval * wp[c * GHID];
    }
    #pragma unroll
    for (int c = 0; c < NC; ++c) {
        acc[c] += __shfl_xor(acc[c], 1);
        acc[c] += __shfl_xor(acc[c], 2);
    }
    if (q == 0) {
        float best = -1e30f; int bi = 0;
        #pragma unroll
        for (int c = 0; c < NC; ++c) {
            acc[c] += b_out[c];
            if (acc[c] > best) { best = acc[c]; bi = c; }   // strict > keeps first max
        }
        if (t < REAL_NL) {
            float* op = out + (size_t)row * (REAL_NL * NC) + (size_t)t * NC;
            #pragma unroll
            for (int c = 0; c < NC; ++c) op[c] = acc[c];
        }
        idx[row] = bi;
    }
}

// ============================================================================
extern "C" void kernel_launch(void* const* d_in, const int* in_sizes, int n_in,
                              void* d_out, int out_size, void* d_ws, size_t ws_size,
                              hipStream_t stream)
{
    const float* z    = (const float*)d_in[1];
    const float* dW   = (const float*)d_in[3];
    const float* db   = (const float*)d_in[4];
    const float* W0   = (const float*)d_in[5];
    const float* g0   = (const float*)d_in[6];
    const float* bb0  = (const float*)d_in[7];
    const float* m0   = (const float*)d_in[8];
    const float* v0   = (const float*)d_in[9];
    const float* al0  = (const float*)d_in[10];
    const float* W1   = (const float*)d_in[11];
    const float* g1   = (const float*)d_in[12];
    const float* bb1  = (const float*)d_in[13];
    const float* m1   = (const float*)d_in[14];
    const float* v1   = (const float*)d_in[15];
    const float* al1  = (const float*)d_in[16];
    const float* W2   = (const float*)d_in[17];
    const float* g2   = (const float*)d_in[18];
    const float* bb2  = (const float*)d_in[19];
    const float* m2   = (const float*)d_in[20];
    const float* v2   = (const float*)d_in[21];
    const float* al2  = (const float*)d_in[22];
    const float* w_px = (const float*)d_in[23];
    const float* b_px = (const float*)d_in[24];
    const float* w_ih = (const float*)d_in[25];
    const float* w_hh = (const float*)d_in[26];
    const float* b_ih = (const float*)d_in[27];
    const float* b_hh = (const float*)d_in[28];
    const float* w_out= (const float*)d_in[29];
    const float* b_out= (const float*)d_in[30];
    float* out = (float*)d_out;

    // ws: hseq(f32) | hA H/L | hB H/L (fp16) | whh H/L | wih H/L | table | idx
    float* ws = (float*)d_ws;
    float* hseq = ws;                                            // 504*2048*42 f32
    _Float16* hAH = (_Float16*)(hseq + (size_t)NLFULL * BATCH * 42);
    _Float16* hAL = hAH + (size_t)BATCH * GHID;
    _Float16* hBH = hAL + (size_t)BATCH * GHID;
    _Float16* hBL = hBH + (size_t)BATCH * GHID;
    _Float16* whhH = hBL + (size_t)BATCH * GHID;                 // 3*32*16*512
    _Float16* whhL = whhH + 3 * 32 * 16 * 512;
    _Float16* wihH = whhL + 3 * 32 * 16 * 512;                   // 3*32*2*512
    _Float16* wihL = wihH + 3 * 32 * 2 * 512;
    float* table = (float*)(wihL + 3 * 32 * 2 * 512);            // 22*1536
    int*   idx   = (int*)(table + 22 * 1536);                    // 2048

    upsample_kernel<<<dim3(BATCH, 4), 512, 0, stream>>>(
        z, dW, db,
        W0, g0, bb0, m0, v0, al0,
        W1, g1, bb1, m1, v1, al1,
        W2, g2, bb2, m2, v2, al2,
        hseq);

    table_kernel<<<(22 * 1536 + 255) / 256, 256, 0, stream>>>(w_px, b_px, w_ih, b_ih, table);
    pack_whh_kernel<<<(3 * 32 * 16 * 512 + 255) / 256, 256, 0, stream>>>(w_hh, whhH, whhL);
    pack_wih_kernel<<<(3 * 32 * 2 * 512 + 255) / 256, 256, 0, stream>>>(w_ih, wihH, wihL);
    init_kernel<<<(BATCH * GHID + 255) / 256, 256, 0, stream>>>(hAH, hAL, idx);

    for (int t = 0; t < NLFULL; ++t) {
        const _Float16* pH = (t & 1) ? hBH : hAH;
        const _Float16* pL = (t & 1) ? hBL : hAL;
        _Float16* nH = (t & 1) ? hAH : hBH;
        _Float16* nL = (t & 1) ? hAL : hBL;
        // gridDim.x = 8 n-tiles -> linear bid % 8 == n-tile == XCD (B stays L2-hot)
        gru_gates_mfma<<<dim3(8, 32), 256, 0, stream>>>(
            pH, pL, hseq + (size_t)t * BATCH * 42, idx, table,
            whhH, whhL, wihH, wihL, b_hh, nH, nL);
        gru_logits<<<32, 256, 0, stream>>>(nH, nL, w_out, b_out, out, idx, t);
    }
}

// Round 5
// 34501.715 us; speedup vs baseline: 1.4460x; 1.4460x over previous
//
#include <hip/hip_runtime.h>
#include <math.h>

#define NLFULL 504
#define REAL_NL 500
#define BATCH 2048
#define NZ 50
#define NC 21
#define GHID 512
#define EPSB 1e-5f
#define LO_SCALE 2048.0f
#define INV_LO (1.0f / 2048.0f)

typedef __attribute__((ext_vector_type(4))) float f32x4;
typedef __attribute__((ext_vector_type(8))) _Float16 half8;

__device__ __forceinline__ void split2(float x, _Float16& hi, _Float16& lo) {
    hi = (_Float16)x;
    lo = (_Float16)((x - (float)hi) * LO_SCALE);
}

// =============================== upsample ==================================
__global__ __launch_bounds__(512) void upsample_kernel(
    const float* __restrict__ z, const float* __restrict__ dW, const float* __restrict__ db,
    const float* __restrict__ W0, const float* __restrict__ g0, const float* __restrict__ bb0,
    const float* __restrict__ m0, const float* __restrict__ v0, const float* __restrict__ al0,
    const float* __restrict__ W1, const float* __restrict__ g1, const float* __restrict__ bb1,
    const float* __restrict__ m1, const float* __restrict__ v1, const float* __restrict__ al1,
    const float* __restrict__ W2, const float* __restrict__ g2, const float* __restrict__ bb2,
    const float* __restrict__ m2, const float* __restrict__ v2, const float* __restrict__ al2,
    float* __restrict__ hseq)
{
    __shared__ float bufA[5712];   // u: [336][17]   then w: [84][65]
    __shared__ float bufB[5544];   // v: [168][33]
    __shared__ float zl[52];

    const int b   = blockIdx.x;
    const int ta  = blockIdx.y * 16;
    const int nt0 = min(16, 63 - ta);
    const int tid = threadIdx.x;

    if (tid < NZ) zl[tid] = z[b * NZ + tid];
    __syncthreads();

    for (int i = tid; i < 336 * nt0; i += 512) {
        int c = i % 336, tt = i / 336;
        int row = c * 63 + ta + tt;
        const float* wr = dW + (size_t)row * NZ;
        float s = db[row];
        #pragma unroll
        for (int n = 0; n < NZ; ++n) s += zl[n] * wr[n];
        bufA[c * 17 + tt] = s;
    }
    __syncthreads();

    const float a0 = al0[0], a1 = al1[0], a2 = al2[0];

    for (int i = tid; i < 168 * 2 * nt0; i += 512) {
        int o = i % 168, tt1 = i / 168;
        int tt = tt1 >> 1, k = tt1 & 1;
        const float* wp = W0 + o * 2 + k;
        float s = 0.f;
        for (int c = 0; c < 336; ++c) s += bufA[c * 17 + tt] * wp[c * 336];
        float sc = g0[o] / sqrtf(v0[o] + EPSB);
        s = (s - m0[o]) * sc + bb0[o];
        s = (s >= 0.f) ? s : a0 * s;
        bufB[o * 33 + tt1] = s;
    }
    __syncthreads();

    for (int i = tid; i < 84 * 4 * nt0; i += 512) {
        int o = i % 84, tt2 = i / 84;
        int tt1 = tt2 >> 1, k = tt2 & 1;
        const float* wp = W1 + o * 2 + k;
        float s = 0.f;
        for (int c = 0; c < 168; ++c) s += bufB[c * 33 + tt1] * wp[c * 168];
        float sc = g1[o] / sqrtf(v1[o] + EPSB);
        s = (s - m1[o]) * sc + bb1[o];
        s = (s >= 0.f) ? s : a1 * s;
        bufA[o * 65 + tt2] = s;
    }
    __syncthreads();

    for (int i = tid; i < 42 * 8 * nt0; i += 512) {
        int o = i % 42, tt3 = i / 42;
        int tt2 = tt3 >> 1, k = tt3 & 1;
        const float* wp = W2 + o * 2 + k;
        float s = 0.f;
        for (int c = 0; c < 84; ++c) s += bufA[c * 65 + tt2] * wp[c * 84];
        float sc = g2[o] / sqrtf(v2[o] + EPSB);
        s = (s - m2[o]) * sc + bb2[o];
        s = (s >= 0.f) ? s : a2 * s;
        int t3 = 8 * ta + tt3;
        hseq[(size_t)t3 * (BATCH * 42) + b * 42 + o] = s;
    }
}

// ================= table: gi-contribution of one-hot px =====================
__global__ void table_kernel(const float* __restrict__ w_px, const float* __restrict__ b_px,
                             const float* __restrict__ w_ih, const float* __restrict__ b_ih,
                             float* __restrict__ table)
{
    int i = blockIdx.x * 256 + threadIdx.x;
    if (i >= 22 * 1536) return;
    int e = i / 1536, jg = i % 1536;
    const float* wih = w_ih + jg * 63 + 42;
    float s = b_ih[jg];
    #pragma unroll
    for (int jp = 0; jp < NC; ++jp) {
        float px = b_px[jp] + (e < NC ? w_px[jp * NC + e] : 0.f);
        s += px * wih[jp];
    }
    table[i] = s;
}

// ====== pack weights into MFMA B-fragment order, fp16 2-limb (lo x2048) =====
// whh: [g][nf(32)][kf(16)][lane(64)*8]; lane l supplies B[k=(l>>4)*8+e][n=l&15]
__global__ void pack_whh_kernel(const float* __restrict__ w_hh,
                                _Float16* __restrict__ pH, _Float16* __restrict__ pL)
{
    int i = blockIdx.x * 256 + threadIdx.x;
    if (i >= 3 * 32 * 16 * 512) return;
    int e = i & 7, l = (i >> 3) & 63, kf = (i >> 9) & 15, nf = (i >> 13) & 31, g = i >> 18;
    int n = nf * 16 + (l & 15);
    int k = kf * 32 + ((l >> 4) << 3) + e;
    float v = w_hh[(size_t)(g * GHID + n) * GHID + k];
    _Float16 hi, lo; split2(v, hi, lo);
    pH[i] = hi; pL[i] = lo;
}

// wih: [g][nf(32)][kf(2)][lane(64)*8], K padded 42 -> 64 with zeros
__global__ void pack_wih_kernel(const float* __restrict__ w_ih,
                                _Float16* __restrict__ pH, _Float16* __restrict__ pL)
{
    int i = blockIdx.x * 256 + threadIdx.x;
    if (i >= 3 * 32 * 2 * 512) return;
    int e = i & 7, l = (i >> 3) & 63, kf = (i >> 9) & 1, nf = (i >> 10) & 31, g = i >> 15;
    int n = nf * 16 + (l & 15);
    int k = kf * 32 + ((l >> 4) << 3) + e;
    float v = (k < 42) ? w_ih[(size_t)(g * GHID + n) * 63 + k] : 0.f;
    _Float16 hi, lo; split2(v, hi, lo);
    pH[i] = hi; pL[i] = lo;
}

// w_out: [nf(2)][kf(16)][lane(64)*8], cols 21..31 zero-padded
__global__ void pack_wout_kernel(const float* __restrict__ w_out,
                                 _Float16* __restrict__ pH, _Float16* __restrict__ pL)
{
    int i = blockIdx.x * 256 + threadIdx.x;
    if (i >= 2 * 16 * 512) return;
    int e = i & 7, l = (i >> 3) & 63, kf = (i >> 9) & 15, nf = i >> 13;
    int n = nf * 16 + (l & 15);
    int k = kf * 32 + ((l >> 4) << 3) + e;
    float v = (n < NC) ? w_out[(size_t)n * GHID + k] : 0.f;
    _Float16 hi, lo; split2(v, hi, lo);
    pH[i] = hi; pL[i] = lo;
}

// ===================== init h0 (fp16 2-limb) ================================
__global__ void init_kernel(_Float16* __restrict__ hH, _Float16* __restrict__ hL)
{
    int i = blockIdx.x * 256 + threadIdx.x;
    if (i < BATCH * GHID) { hH[i] = (_Float16)0.f; hL[i] = (_Float16)0.f; }
}

// ==================== fused per-step kernel =================================
// grid (16 n-tiles, 16 m-tiles), 512 thr = 8 waves. Block tile 128M x 32N x 3g.
// gridDim.x=16 -> XCD = x%8 owns 2 n-slices; packed B slice (393 KB) L2-resident
// across all steps. Phase 1: logits(h_prev)+argmax for the block's 128 rows
// (duplicated across n-blocks, bit-identical). Phase 2: GRU gates -> h_new.
#define MFMA3(mainA, crossA, aH_, aL_, bH_, bL_)                                   \
    mainA  = __builtin_amdgcn_mfma_f32_16x16x32_f16(aH_, bH_, mainA, 0, 0, 0);     \
    crossA = __builtin_amdgcn_mfma_f32_16x16x32_f16(aH_, bL_, crossA, 0, 0, 0);    \
    crossA = __builtin_amdgcn_mfma_f32_16x16x32_f16(aL_, bH_, crossA, 0, 0, 0);

__global__ __launch_bounds__(512, 2) void gru_step(
    const _Float16* __restrict__ hpH, const _Float16* __restrict__ hpL,
    const float* __restrict__ ht,          // hseq + t*B*42
    const float* __restrict__ table,
    const _Float16* __restrict__ whhH, const _Float16* __restrict__ whhL,
    const _Float16* __restrict__ wihH, const _Float16* __restrict__ wihL,
    const float* __restrict__ b_hh,
    const _Float16* __restrict__ woH, const _Float16* __restrict__ woL,
    const float* __restrict__ b_out,
    float* __restrict__ out, int t,
    _Float16* __restrict__ hnH, _Float16* __restrict__ hnL)
{
    __shared__ float lg[128][33];
    __shared__ int   idx_lds[128];

    const int tid  = threadIdx.x;
    const int l    = tid & 63;
    const int wv   = tid >> 6;            // 0..7
    const int m0   = blockIdx.y * 128;
    const int lrow = l & 15;
    const int lk   = (l >> 4) << 3;

    // ---------------- phase 1: logits + argmax on h_prev --------------------
    if (t > 0) {
        const size_t ar = (size_t)(m0 + wv * 16 + lrow) * GHID + lk;
        f32x4 accM[2], accX[2];
        accM[0] = (f32x4)0.f; accM[1] = (f32x4)0.f;
        accX[0] = (f32x4)0.f; accX[1] = (f32x4)0.f;
        for (int kf = 0; kf < 16; ++kf) {
            half8 aH = *(const half8*)(hpH + ar + kf * 32);
            half8 aL = *(const half8*)(hpL + ar + kf * 32);
            #pragma unroll
            for (int nf = 0; nf < 2; ++nf) {
                size_t bo = ((size_t)(nf * 16 + kf) << 9) + (l << 3);
                half8 bH = *(const half8*)(woH + bo);
                half8 bL = *(const half8*)(woL + bo);
                MFMA3(accM[nf], accX[nf], aH, aL, bH, bL);
            }
        }
        #pragma unroll
        for (int nf = 0; nf < 2; ++nf) {
            int col = nf * 16 + lrow;
            float bias = (col < NC) ? b_out[col] : 0.f;
            #pragma unroll
            for (int r = 0; r < 4; ++r) {
                int row = wv * 16 + ((l >> 4) << 2) + r;
                lg[row][col] = accM[nf][r] + accX[nf][r] * INV_LO + bias;
            }
        }
    }
    __syncthreads();
    if (tid < 128) {
        if (t > 0) {
            float best = lg[tid][0]; int bi = 0;
            #pragma unroll
            for (int c = 1; c < NC; ++c) {
                float v = lg[tid][c];
                if (v > best) { best = v; bi = c; }   // strict > keeps first max
            }
            idx_lds[tid] = bi;
            if (blockIdx.x == 0) {
                float* op = out + (size_t)(m0 + tid) * (REAL_NL * NC) + (size_t)(t - 1) * NC;
                #pragma unroll
                for (int c = 0; c < NC; ++c) op[c] = lg[tid][c];
            }
        } else {
            idx_lds[tid] = NC;   // zeros-x1h table entry
        }
    }
    __syncthreads();

    if (t >= REAL_NL) return;    // t == REAL_NL: logits-only launch

    // ---------------- phase 2: GRU gates ------------------------------------
    const int wM = wv >> 1, wN = wv & 1;          // 4 x 2 wave grid
    const int mw = m0 + wM * 32;
    const int nf = blockIdx.x * 2 + wN;           // global nf 0..31

    // streams: 0=r, 1=z, 2=in(I part), 3=hn(H part)
    f32x4 aM[4][2], aX[4][2];
    #pragma unroll
    for (int s = 0; s < 4; ++s)
        #pragma unroll
        for (int mi = 0; mi < 2; ++mi) { aM[s][mi] = (f32x4)0.f; aX[s][mi] = (f32x4)0.f; }

    const size_t arow0 = (size_t)(mw + lrow) * GHID + lk;
    const size_t arow1 = arow0 + 16 * GHID;

    // H part: K = 512 = 16 k-frags
    for (int kf = 0; kf < 16; ++kf) {
        half8 aHf[2], aLf[2];
        aHf[0] = *(const half8*)(hpH + arow0 + kf * 32);
        aLf[0] = *(const half8*)(hpL + arow0 + kf * 32);
        aHf[1] = *(const half8*)(hpH + arow1 + kf * 32);
        aLf[1] = *(const half8*)(hpL + arow1 + kf * 32);
        #pragma unroll
        for (int g = 0; g < 3; ++g) {
            size_t bo = ((size_t)((g * 32 + nf) * 16 + kf) << 9) + (l << 3);
            half8 bH = *(const half8*)(whhH + bo);
            half8 bL = *(const half8*)(whhL + bo);
            const int s = (g == 2) ? 3 : g;
            #pragma unroll
            for (int mi = 0; mi < 2; ++mi) {
                MFMA3(aM[s][mi], aX[s][mi], aHf[mi], aLf[mi], bH, bL);
            }
        }
    }

    // I part: K = 42 (2 k-frags, on-the-fly fp32 -> 2-limb split)
    #pragma unroll
    for (int kf = 0; kf < 2; ++kf) {
        half8 aHf[2], aLf[2];
        #pragma unroll
        for (int mi = 0; mi < 2; ++mi) {
            const float* rp = ht + (size_t)(mw + mi * 16 + lrow) * 42;
            #pragma unroll
            for (int e = 0; e < 8; ++e) {
                int k = kf * 32 + lk + e;
                float f = (k < 42) ? rp[k] : 0.f;
                _Float16 hi, lo; split2(f, hi, lo);
                aHf[mi][e] = hi; aLf[mi][e] = lo;
            }
        }
        #pragma unroll
        for (int g = 0; g < 3; ++g) {
            size_t bo = ((size_t)((g * 32 + nf) * 2 + kf) << 9) + (l << 3);
            half8 bH = *(const half8*)(wihH + bo);
            half8 bL = *(const half8*)(wihL + bo);
            const int s = (g == 2) ? 2 : g;
            #pragma unroll
            for (int mi = 0; mi < 2; ++mi) {
                MFMA3(aM[s][mi], aX[s][mi], aHf[mi], aLf[mi], bH, bL);
            }
        }
    }

    // epilogue: D layout row=(l>>4)*4+r, col=l&15
    const int c = nf * 16 + lrow;
    const float bhr = b_hh[c], bhz = b_hh[GHID + c], bhn = b_hh[2 * GHID + c];
    #pragma unroll
    for (int mi = 0; mi < 2; ++mi) {
        #pragma unroll
        for (int r = 0; r < 4; ++r) {
            int lm = wM * 32 + mi * 16 + ((l >> 4) << 2) + r;   // local row 0..127
            int m = m0 + lm;
            const float* tb = table + idx_lds[lm] * 1536;
            float rv  = aM[0][mi][r] + aX[0][mi][r] * INV_LO + bhr + tb[c];
            float zv  = aM[1][mi][r] + aX[1][mi][r] * INV_LO + bhz + tb[GHID + c];
            float inp = aM[2][mi][r] + aX[2][mi][r] * INV_LO + tb[2 * GHID + c];
            float hnp = aM[3][mi][r] + aX[3][mi][r] * INV_LO + bhn;
            float rg = 1.f / (1.f + expf(-rv));
            float zg = 1.f / (1.f + expf(-zv));
            float ng = tanhf(inp + rg * hnp);
            size_t off = (size_t)m * GHID + c;
            float hpv = (float)hpH[off] + (float)hpL[off] * INV_LO;
            float hnv = (1.f - zg) * ng + zg * hpv;
            _Float16 hi, lo; split2(hnv, hi, lo);
            hnH[off] = hi; hnL[off] = lo;
        }
    }
}

// ============================================================================
extern "C" void kernel_launch(void* const* d_in, const int* in_sizes, int n_in,
                              void* d_out, int out_size, void* d_ws, size_t ws_size,
                              hipStream_t stream)
{
    const float* z    = (const float*)d_in[1];
    const float* dW   = (const float*)d_in[3];
    const float* db   = (const float*)d_in[4];
    const float* W0   = (const float*)d_in[5];
    const float* g0   = (const float*)d_in[6];
    const float* bb0  = (const float*)d_in[7];
    const float* m0   = (const float*)d_in[8];
    const float* v0   = (const float*)d_in[9];
    const float* al0  = (const float*)d_in[10];
    const float* W1   = (const float*)d_in[11];
    const float* g1   = (const float*)d_in[12];
    const float* bb1  = (const float*)d_in[13];
    const float* m1   = (const float*)d_in[14];
    const float* v1   = (const float*)d_in[15];
    const float* al1  = (const float*)d_in[16];
    const float* W2   = (const float*)d_in[17];
    const float* g2   = (const float*)d_in[18];
    const float* bb2  = (const float*)d_in[19];
    const float* m2   = (const float*)d_in[20];
    const float* v2   = (const float*)d_in[21];
    const float* al2  = (const float*)d_in[22];
    const float* w_px = (const float*)d_in[23];
    const float* b_px = (const float*)d_in[24];
    const float* w_ih = (const float*)d_in[25];
    const float* w_hh = (const float*)d_in[26];
    const float* b_ih = (const float*)d_in[27];
    const float* b_hh = (const float*)d_in[28];
    const float* w_out= (const float*)d_in[29];
    const float* b_out= (const float*)d_in[30];
    float* out = (float*)d_out;

    // ws: hseq(f32) | hA H/L | hB H/L | whh H/L | wih H/L | wout H/L | table
    float* ws = (float*)d_ws;
    float* hseq = ws;                                            // 504*2048*42 f32
    _Float16* hAH = (_Float16*)(hseq + (size_t)NLFULL * BATCH * 42);
    _Float16* hAL = hAH + (size_t)BATCH * GHID;
    _Float16* hBH = hAL + (size_t)BATCH * GHID;
    _Float16* hBL = hBH + (size_t)BATCH * GHID;
    _Float16* whhH = hBL + (size_t)BATCH * GHID;                 // 3*32*16*512
    _Float16* whhL = whhH + 3 * 32 * 16 * 512;
    _Float16* wihH = whhL + 3 * 32 * 16 * 512;                   // 3*32*2*512
    _Float16* wihL = wihH + 3 * 32 * 2 * 512;
    _Float16* woH  = wihL + 3 * 32 * 2 * 512;                    // 2*16*512
    _Float16* woL  = woH + 2 * 16 * 512;
    float* table = (float*)(woL + 2 * 16 * 512);                 // 22*1536

    upsample_kernel<<<dim3(BATCH, 4), 512, 0, stream>>>(
        z, dW, db,
        W0, g0, bb0, m0, v0, al0,
        W1, g1, bb1, m1, v1, al1,
        W2, g2, bb2, m2, v2, al2,
        hseq);

    table_kernel<<<(22 * 1536 + 255) / 256, 256, 0, stream>>>(w_px, b_px, w_ih, b_ih, table);
    pack_whh_kernel<<<(3 * 32 * 16 * 512 + 255) / 256, 256, 0, stream>>>(w_hh, whhH, whhL);
    pack_wih_kernel<<<(3 * 32 * 2 * 512 + 255) / 256, 256, 0, stream>>>(w_ih, wihH, wihL);
    pack_wout_kernel<<<(2 * 16 * 512 + 255) / 256, 256, 0, stream>>>(w_out, woH, woL);
    init_kernel<<<(BATCH * GHID + 255) / 256, 256, 0, stream>>>(hAH, hAL);

    // t = 0..REAL_NL: step t does logits(h[t-1]) -> out[t-1], then gates -> h[t]
    for (int t = 0; t <= REAL_NL; ++t) {
        const _Float16* pH = (t & 1) ? hBH : hAH;
        const _Float16* pL = (t & 1) ? hBL : hAL;
        _Float16* nH = (t & 1) ? hAH : hBH;
        _Float16* nL = (t & 1) ? hAL : hBL;
        gru_step<<<dim3(16, 16), 512, 0, stream>>>(
            pH, pL, hseq + (size_t)t * BATCH * 42, table,
            whhH, whhL, wihH, wihL, b_hh,
            woH, woL, b_out, out, t, nH, nL);
    }
}